// Round 1
// baseline (102.170 us; speedup 1.0000x reference)
//
#include <hip/hip_runtime.h>
#include <math.h>

// ---------------------------------------------------------------------------
// 4-qubit statevector simulation, one thread per (batch, patch) circuit.
// State: 16 complex amps in registers. Qubit q == bit (3-q) of the flat index.
// ---------------------------------------------------------------------------

#define PI_F 3.14159265358979323846f

template<int M>
__device__ __forceinline__ void apply_ry(float2 s[16], float c, float sn) {
#pragma unroll
  for (int i = 0; i < 16; ++i) {
    if (!(i & M)) {
      float2 a = s[i], b = s[i | M];
      s[i]     = make_float2(c * a.x - sn * b.x, c * a.y - sn * b.y);
      s[i | M] = make_float2(sn * a.x + c * b.x, sn * a.y + c * b.y);
    }
  }
}

// Rx: [[c, -i s], [-i s, c]]
template<int M>
__device__ __forceinline__ void apply_rx(float2 s[16], float c, float sn) {
#pragma unroll
  for (int i = 0; i < 16; ++i) {
    if (!(i & M)) {
      float2 a = s[i], b = s[i | M];
      s[i]     = make_float2(c * a.x + sn * b.y, c * a.y - sn * b.x);
      s[i | M] = make_float2(sn * a.y + c * b.x, -sn * a.x + c * b.y);
    }
  }
}

// Rz: diag(e^{-it/2}, e^{+it/2}); c=cos(t/2), sn=sin(t/2)
template<int M>
__device__ __forceinline__ void apply_rz(float2 s[16], float c, float sn) {
#pragma unroll
  for (int i = 0; i < 16; ++i) {
    float2 a = s[i];
    if (i & M) s[i] = make_float2(a.x * c - a.y * sn, a.y * c + a.x * sn);
    else       s[i] = make_float2(a.x * c + a.y * sn, a.y * c - a.x * sn);
  }
}

template<int MC, int MT>
__device__ __forceinline__ void apply_cnot(float2 s[16]) {
#pragma unroll
  for (int i = 0; i < 16; ++i) {
    if ((i & MC) && !(i & MT)) {
      float2 t = s[i]; s[i] = s[i | MT]; s[i | MT] = t;
    }
  }
}

__global__ __launch_bounds__(256) void qsim_kernel(
    const float* __restrict__ x,      // [128,1,28,28]
    const float* __restrict__ w,      // [60]
    float* __restrict__ feat) {       // [128,784]  (b, p*4+q)
  __shared__ float wc[60], wsn[60];
  const int t = threadIdx.x;
  if (t < 60) {
    float s_, c_;
    sincosf(w[t] * 0.5f, &s_, &c_);
    wsn[t] = s_; wc[t] = c_;
  }
  __syncthreads();

  const int idx = blockIdx.x * 256 + t;          // circuit id
  if (idx >= 128 * 196) return;
  const int b = idx / 196;
  const int p = idx - b * 196;                   // patch 0..195
  const int pi = p / 14, pj = p - pi * 14;

  const float* xb = x + b * 784 + (2 * pi) * 28 + 2 * pj;
  const float a0 = xb[0], a1 = xb[1], a2 = xb[28], a3 = xb[29];

  float2 s[16];
#pragma unroll
  for (int i = 0; i < 16; ++i) s[i] = make_float2(0.f, 0.f);
  s[0] = make_float2(1.f, 0.f);

  // Rx encoding: theta = 2*pi*x  =>  theta/2 = pi*x
  float c_, s_;
  sincosf(PI_F * a0, &s_, &c_); apply_rx<8>(s, c_, s_);
  sincosf(PI_F * a1, &s_, &c_); apply_rx<4>(s, c_, s_);
  sincosf(PI_F * a2, &s_, &c_); apply_rx<2>(s, c_, s_);
  sincosf(PI_F * a3, &s_, &c_); apply_rx<1>(s, c_, s_);

#pragma unroll
  for (int l = 0; l < 5; ++l) {
    const float* lc = wc + 12 * l;
    const float* ls = wsn + 12 * l;
    apply_ry<8>(s, lc[0], ls[0]);
    apply_ry<4>(s, lc[1], ls[1]);
    apply_ry<2>(s, lc[2], ls[2]);
    apply_ry<1>(s, lc[3], ls[3]);
    apply_rz<8>(s, lc[4], ls[4]);
    apply_rz<4>(s, lc[5], ls[5]);
    apply_rz<2>(s, lc[6], ls[6]);
    apply_rz<1>(s, lc[7], ls[7]);
    apply_ry<8>(s, lc[8],  ls[8]);
    apply_ry<4>(s, lc[9],  ls[9]);
    apply_ry<2>(s, lc[10], ls[10]);
    apply_ry<1>(s, lc[11], ls[11]);
    if (l < 4) {
      apply_cnot<8, 4>(s);   // CNOT(0,1)
      apply_cnot<4, 2>(s);   // CNOT(1,2)
      apply_cnot<2, 1>(s);   // CNOT(2,3)
      apply_cnot<1, 8>(s);   // CNOT(3,0)
    }
  }

  float e0 = 0.f, e1 = 0.f, e2 = 0.f, e3 = 0.f;
#pragma unroll
  for (int i = 0; i < 16; ++i) {
    const float pr = s[i].x * s[i].x + s[i].y * s[i].y;
    e0 += (i & 8) ? -pr : pr;
    e1 += (i & 4) ? -pr : pr;
    e2 += (i & 2) ? -pr : pr;
    e3 += (i & 1) ? -pr : pr;
  }
  float* f = feat + b * 784 + p * 4;
  f[0] = e0; f[1] = e1; f[2] = e2; f[3] = e3;
}

// ---------------------------------------------------------------------------
// MLP head: h = relu(feat @ fc1_w.T + fc1_b); out = h @ fc2_w.T + fc2_b
// one 64-thread block per batch row
// ---------------------------------------------------------------------------
__global__ __launch_bounds__(64) void fc_kernel(
    const float* __restrict__ feat,   // [128,784]
    const float* __restrict__ w1,     // [64,784]
    const float* __restrict__ b1,     // [64]
    const float* __restrict__ w2,     // [10,64]
    const float* __restrict__ b2,     // [10]
    float* __restrict__ out) {        // [128,10]
  __shared__ float f[784];
  __shared__ float h[64];
  const int b = blockIdx.x, t = threadIdx.x;

  const float* fr = feat + b * 784;
  for (int k = t; k < 784; k += 64) f[k] = fr[k];
  __syncthreads();

  const float* wr = w1 + t * 784;
  float acc = b1[t];
#pragma unroll 4
  for (int k = 0; k < 784; ++k) acc = fmaf(f[k], wr[k], acc);
  h[t] = fmaxf(acc, 0.f);
  __syncthreads();

  if (t < 10) {
    float o = b2[t];
    const float* w2r = w2 + t * 64;
#pragma unroll
    for (int k = 0; k < 64; ++k) o = fmaf(h[k], w2r[k], o);
    out[b * 10 + t] = o;
  }
}

extern "C" void kernel_launch(void* const* d_in, const int* in_sizes, int n_in,
                              void* d_out, int out_size, void* d_ws, size_t ws_size,
                              hipStream_t stream) {
  const float* x    = (const float*)d_in[0];   // [128,1,28,28]
  const float* w    = (const float*)d_in[1];   // [60]
  const float* w1   = (const float*)d_in[2];   // [64,784]
  const float* b1   = (const float*)d_in[3];   // [64]
  const float* w2   = (const float*)d_in[4];   // [10,64]
  const float* b2   = (const float*)d_in[5];   // [10]
  float* out = (float*)d_out;                  // [128,10]
  float* feat = (float*)d_ws;                  // [128,784] scratch

  const int L = 128 * 196;                     // 25088 circuits
  qsim_kernel<<<(L + 255) / 256, 256, 0, stream>>>(x, w, feat);
  fc_kernel<<<128, 64, 0, stream>>>(feat, w1, b1, w2, b2, out);
}

// Round 2
// 83.747 us; speedup vs baseline: 1.2200x; 1.2200x over previous
//
#include <hip/hip_runtime.h>
#include <math.h>

// ---------------------------------------------------------------------------
// Fully fused: per batch row (block), 196 4-qubit circuits (threads 0..195,
// state = 16 complex amps in registers) -> features in LDS -> fc1 (4 waves,
// coalesced w1 reads, shuffle reduce) -> fc2 (10 threads) -> out.
// Qubit q == bit (3-q) of the flat amplitude index.
// ---------------------------------------------------------------------------

#define PI_F 3.14159265358979323846f

template<int M>
__device__ __forceinline__ void apply_ry(float2 s[16], float c, float sn) {
#pragma unroll
  for (int i = 0; i < 16; ++i) {
    if (!(i & M)) {
      float2 a = s[i], b = s[i | M];
      s[i]     = make_float2(c * a.x - sn * b.x, c * a.y - sn * b.y);
      s[i | M] = make_float2(sn * a.x + c * b.x, sn * a.y + c * b.y);
    }
  }
}

// Rx: [[c, -i s], [-i s, c]]
template<int M>
__device__ __forceinline__ void apply_rx(float2 s[16], float c, float sn) {
#pragma unroll
  for (int i = 0; i < 16; ++i) {
    if (!(i & M)) {
      float2 a = s[i], b = s[i | M];
      s[i]     = make_float2(c * a.x + sn * b.y, c * a.y - sn * b.x);
      s[i | M] = make_float2(sn * a.y + c * b.x, -sn * a.x + c * b.y);
    }
  }
}

// Rz: diag(e^{-it/2}, e^{+it/2}); c=cos(t/2), sn=sin(t/2)
template<int M>
__device__ __forceinline__ void apply_rz(float2 s[16], float c, float sn) {
#pragma unroll
  for (int i = 0; i < 16; ++i) {
    float2 a = s[i];
    if (i & M) s[i] = make_float2(a.x * c - a.y * sn, a.y * c + a.x * sn);
    else       s[i] = make_float2(a.x * c + a.y * sn, a.y * c - a.x * sn);
  }
}

template<int MC, int MT>
__device__ __forceinline__ void apply_cnot(float2 s[16]) {
#pragma unroll
  for (int i = 0; i < 16; ++i) {
    if ((i & MC) && !(i & MT)) {
      float2 t = s[i]; s[i] = s[i | MT]; s[i | MT] = t;
    }
  }
}

__global__ __launch_bounds__(256) void fused_qnet_kernel(
    const float* __restrict__ x,      // [128,1,28,28]
    const float* __restrict__ w,      // [60]
    const float* __restrict__ w1,     // [64,784]
    const float* __restrict__ b1,     // [64]
    const float* __restrict__ w2,     // [10,64]
    const float* __restrict__ b2,     // [10]
    float* __restrict__ out) {        // [128,10]
  __shared__ float wc[60], wsn[60];
  __shared__ float f[784];            // feature row of this batch element
  __shared__ float h[64];             // fc1 activations

  const int t = threadIdx.x;
  const int b = blockIdx.x;

  if (t < 60) {
    float s_, c_;
    __sincosf(w[t] * 0.5f, &s_, &c_);   // angles in [0, 2pi) -> args in [0, pi)
    wsn[t] = s_; wc[t] = c_;
  }
  __syncthreads();

  // ---------------- phase 1: quantum circuits (threads 0..195) -------------
  if (t < 196) {
    const int pi_ = t / 14, pj = t - pi_ * 14;
    const float* xb = x + b * 784 + (2 * pi_) * 28 + 2 * pj;
    const float a0 = xb[0], a1 = xb[1], a2 = xb[28], a3 = xb[29];

    float2 s[16];
#pragma unroll
    for (int i = 0; i < 16; ++i) s[i] = make_float2(0.f, 0.f);
    s[0] = make_float2(1.f, 0.f);

    float c_, s_;
    __sincosf(PI_F * a0, &s_, &c_); apply_rx<8>(s, c_, s_);
    __sincosf(PI_F * a1, &s_, &c_); apply_rx<4>(s, c_, s_);
    __sincosf(PI_F * a2, &s_, &c_); apply_rx<2>(s, c_, s_);
    __sincosf(PI_F * a3, &s_, &c_); apply_rx<1>(s, c_, s_);

#pragma unroll
    for (int l = 0; l < 5; ++l) {
      const float* lc = wc + 12 * l;
      const float* ls = wsn + 12 * l;
      apply_ry<8>(s, lc[0], ls[0]);
      apply_ry<4>(s, lc[1], ls[1]);
      apply_ry<2>(s, lc[2], ls[2]);
      apply_ry<1>(s, lc[3], ls[3]);
      apply_rz<8>(s, lc[4], ls[4]);
      apply_rz<4>(s, lc[5], ls[5]);
      apply_rz<2>(s, lc[6], ls[6]);
      apply_rz<1>(s, lc[7], ls[7]);
      apply_ry<8>(s, lc[8],  ls[8]);
      apply_ry<4>(s, lc[9],  ls[9]);
      apply_ry<2>(s, lc[10], ls[10]);
      apply_ry<1>(s, lc[11], ls[11]);
      if (l < 4) {
        apply_cnot<8, 4>(s);   // CNOT(0,1)
        apply_cnot<4, 2>(s);   // CNOT(1,2)
        apply_cnot<2, 1>(s);   // CNOT(2,3)
        apply_cnot<1, 8>(s);   // CNOT(3,0)
      }
    }

    float e0 = 0.f, e1 = 0.f, e2 = 0.f, e3 = 0.f;
#pragma unroll
    for (int i = 0; i < 16; ++i) {
      const float pr = s[i].x * s[i].x + s[i].y * s[i].y;
      e0 += (i & 8) ? -pr : pr;
      e1 += (i & 4) ? -pr : pr;
      e2 += (i & 2) ? -pr : pr;
      e3 += (i & 1) ? -pr : pr;
    }
    float4* fv = (float4*)(f + t * 4);
    *fv = make_float4(e0, e1, e2, e3);
  }
  __syncthreads();

  // ---------------- phase 2: fc1 (64 outputs, 4 waves x 16) ----------------
  const int wv = t >> 6;        // wave 0..3
  const int l  = t & 63;        // lane

  // hoist feature fragment into registers (shared across the 16 outputs)
  float fr[12];
#pragma unroll
  for (int it = 0; it < 12; ++it) fr[it] = f[it * 64 + l];
  const float ft = (l < 16) ? f[768 + l] : 0.f;

#pragma unroll
  for (int jj = 0; jj < 16; ++jj) {
    const int j = wv * 16 + jj;
    const float* wr = w1 + j * 784;
    float acc = (l < 16) ? ft * wr[768 + l] : 0.f;
#pragma unroll
    for (int it = 0; it < 12; ++it)
      acc = fmaf(fr[it], wr[it * 64 + l], acc);
#pragma unroll
    for (int off = 32; off > 0; off >>= 1)
      acc += __shfl_down(acc, off, 64);
    if (l == 0) h[j] = fmaxf(acc + b1[j], 0.f);
  }
  __syncthreads();

  // ---------------- phase 3: fc2 (10 outputs) ------------------------------
  if (t < 10) {
    float o = b2[t];
    const float* w2r = w2 + t * 64;
#pragma unroll
    for (int k = 0; k < 64; ++k) o = fmaf(h[k], w2r[k], o);
    out[b * 10 + t] = o;
  }
}

extern "C" void kernel_launch(void* const* d_in, const int* in_sizes, int n_in,
                              void* d_out, int out_size, void* d_ws, size_t ws_size,
                              hipStream_t stream) {
  const float* x    = (const float*)d_in[0];   // [128,1,28,28]
  const float* w    = (const float*)d_in[1];   // [60]
  const float* w1   = (const float*)d_in[2];   // [64,784]
  const float* b1   = (const float*)d_in[3];   // [64]
  const float* w2   = (const float*)d_in[4];   // [10,64]
  const float* b2   = (const float*)d_in[5];   // [10]
  float* out = (float*)d_out;                  // [128,10]

  fused_qnet_kernel<<<128, 256, 0, stream>>>(x, w, w1, b1, w2, b2, out);
}